// Round 1
// baseline (9570.786 us; speedup 1.0000x reference)
//
#include <hip/hip_runtime.h>
#include <math.h>

#define B_ 2
#define T_ 2048
#define D_ 1024
#define H_ 16
#define HD_ 64
#define EPS_ 1.1920929e-07f
#define VE_SCALE_ 2.0f

#define BM 64
#define BN 64
#define BKK 16

// C[M,N] = scale * A[M,K] @ W[N,K]^T   (both row-major, K contiguous)
__global__ __launch_bounds__(256) void gemm_xwT(
    const float* __restrict__ A, const float* __restrict__ W,
    float* __restrict__ C, int M, int N, int K,
    const float* __restrict__ lam, int li)
{
  const float scale = lam[li];
  __shared__ float As[BKK][BM + 4];
  __shared__ float Bs[BKK][BN + 4];
  const int tid = threadIdx.x;
  const int tx = tid & 15, ty = tid >> 4;
  const int row0 = blockIdx.y * BM, col0 = blockIdx.x * BN;
  const int lr = tid >> 2;          // 0..63
  const int lk = (tid & 3) << 2;    // 0,4,8,12
  const float* Ap = A + (size_t)(row0 + lr) * K + lk;
  const float* Wp = W + (size_t)(col0 + lr) * K + lk;
  float acc[4][4] = {};
  for (int k0 = 0; k0 < K; k0 += BKK) {
    const float4 av = *(const float4*)(Ap + k0);
    const float4 bv = *(const float4*)(Wp + k0);
    __syncthreads();
    As[lk + 0][lr] = av.x; As[lk + 1][lr] = av.y;
    As[lk + 2][lr] = av.z; As[lk + 3][lr] = av.w;
    Bs[lk + 0][lr] = bv.x; Bs[lk + 1][lr] = bv.y;
    Bs[lk + 2][lr] = bv.z; Bs[lk + 3][lr] = bv.w;
    __syncthreads();
#pragma unroll
    for (int kk = 0; kk < BKK; ++kk) {
      const float4 a4 = *(const float4*)&As[kk][ty << 2];
      const float4 b4 = *(const float4*)&Bs[kk][tx << 2];
      const float a[4] = {a4.x, a4.y, a4.z, a4.w};
      const float b[4] = {b4.x, b4.y, b4.z, b4.w};
#pragma unroll
      for (int i = 0; i < 4; ++i)
#pragma unroll
        for (int j = 0; j < 4; ++j)
          acc[i][j] = fmaf(a[i], b[j], acc[i][j]);
    }
  }
#pragma unroll
  for (int i = 0; i < 4; ++i) {
    float4 o;
    o.x = acc[i][0] * scale; o.y = acc[i][1] * scale;
    o.z = acc[i][2] * scale; o.w = acc[i][3] * scale;
    *(float4*)&C[(size_t)(row0 + (ty << 2) + i) * N + col0 + (tx << 2)] = o;
  }
}

// one wave per (b,t,h): both sigmoid gates
__global__ __launch_bounds__(256) void gates_kernel(
    const float* __restrict__ x, const float* __restrict__ agw,
    const float* __restrict__ vgw, float* __restrict__ attn_gate,
    float* __restrict__ ve_gate2)
{
  const int wid = (blockIdx.x * blockDim.x + threadIdx.x) >> 6;
  const int lane = threadIdx.x & 63;
  const int h = wid & (H_ - 1);
  const int t = (wid >> 4) & (T_ - 1);
  const int b = wid >> 15;
  const float* xp = x + (size_t)(b * T_ + t) * D_;
  const float* ap = agw + (size_t)h * D_;
  const float* vp = vgw + (size_t)h * D_;
  float sa = 0.f, sv = 0.f;
#pragma unroll
  for (int i = 0; i < D_ / 64; ++i) {
    const float xv = xp[lane + (i << 6)];
    sa = fmaf(xv, ap[lane + (i << 6)], sa);
    sv = fmaf(xv, vp[lane + (i << 6)], sv);
  }
#pragma unroll
  for (int off = 32; off > 0; off >>= 1) {
    sa += __shfl_down(sa, off);
    sv += __shfl_down(sv, off);
  }
  if (lane == 0) {
    const int idx = (b * T_ + t) * H_ + h;
    attn_gate[idx] = 1.f / (1.f + __expf(-sa));
    ve_gate2[idx] = VE_SCALE_ / (1.f + __expf(-sv));
  }
}

// one wave per (b,t,h): rmsnorm + rotary for q,k ; v += ve_gate*ve
// writes q_buf/k_tmp/v_buf in (B,H,T,HD) layout
__global__ __launch_bounds__(256) void post_kernel(
    const float* __restrict__ qkv_raw, const float* __restrict__ ve,
    const float* __restrict__ cosb, const float* __restrict__ sinb,
    const float* __restrict__ ve_gate2,
    float* __restrict__ q_buf, float* __restrict__ k_tmp,
    float* __restrict__ v_buf)
{
  const int wid = (blockIdx.x * blockDim.x + threadIdx.x) >> 6;
  const int lane = threadIdx.x & 63;
  const int h = wid & (H_ - 1);
  const int t = (wid >> 4) & (T_ - 1);
  const int b = wid >> 15;
  const size_t row = (size_t)(b * T_ + t) * (3 * D_);
  const float qraw = qkv_raw[row + h * HD_ + lane];
  const float kraw = qkv_raw[row + D_ + h * HD_ + lane];
  const float vraw = qkv_raw[row + 2 * D_ + h * HD_ + lane];
  const float c = cosb[t * (HD_ / 2) + (lane & 31)];
  const float s = sinb[t * (HD_ / 2) + (lane & 31)];

  float ssq = qraw * qraw;
  float ssk = kraw * kraw;
#pragma unroll
  for (int off = 32; off > 0; off >>= 1) {
    ssq += __shfl_xor(ssq, off);
    ssk += __shfl_xor(ssk, off);
  }
  const float qn = qraw * rsqrtf(ssq * (1.f / 64.f) + EPS_);
  const float kn = kraw * rsqrtf(ssk * (1.f / 64.f) + EPS_);
  const float qpartner = __shfl_xor(qn, 32);
  const float kpartner = __shfl_xor(kn, 32);
  const float qo = (lane < 32) ? fmaf(qn, c, qpartner * s)
                               : fmaf(qn, c, -qpartner * s);
  const float ko = (lane < 32) ? fmaf(kn, c, kpartner * s)
                               : fmaf(kn, c, -kpartner * s);
  const int bh = b * H_ + h;
  q_buf[((size_t)bh * T_ + t) * HD_ + lane] = qo;
  k_tmp[((size_t)bh * T_ + t) * HD_ + lane] = ko;
  const float g = ve_gate2[(b * T_ + t) * H_ + h];
  const float vv = fmaf(g, ve[(size_t)(b * T_ + t) * D_ + h * HD_ + lane], vraw);
  v_buf[((size_t)bh * T_ + t) * HD_ + lane] = vv;
}

// KEY_OFFSET: channels [16,32) and [48,64) come from t-1 (t>0)
__global__ __launch_bounds__(256) void koffset_kernel(
    const float* __restrict__ k_tmp, float* __restrict__ k_buf)
{
  const int idx = blockIdx.x * 256 + threadIdx.x;  // < B*H*T*HD
  const int d = idx & 63;
  const int t = (idx >> 6) & (T_ - 1);
  const int bh = idx >> 17;
  const bool off = ((d >= 16) & (d < 32)) | (d >= 48);
  const int ts = (off && t > 0) ? t - 1 : t;
  k_buf[idx] = k_tmp[((size_t)bh * T_ + ts) * HD_ + d];
}

// flash attention: 1 wave per block, thread r owns q-row qt*64+r
__global__ __launch_bounds__(64) void attn_kernel(
    const float* __restrict__ q_buf, const float* __restrict__ k_buf,
    const float* __restrict__ v_buf, const float* __restrict__ attn_gate,
    const int* __restrict__ docs, const float* __restrict__ scale_ptr,
    float* __restrict__ y_buf)
{
  const int qt = blockIdx.x;
  const int bh = blockIdx.y;
  const int b = bh >> 4, h = bh & 15;
  const int lane = threadIdx.x;
  const int qpos = qt * 64 + lane;
  const float scale = scale_ptr[0];
  const float* qp = q_buf + ((size_t)bh * T_ + qpos) * HD_;
  float q[HD_];
#pragma unroll
  for (int d = 0; d < HD_; d += 4) {
    const float4 v4 = *(const float4*)(qp + d);
    q[d] = v4.x; q[d + 1] = v4.y; q[d + 2] = v4.z; q[d + 3] = v4.w;
  }
  const int docq = docs[qpos];
  float acc[HD_];
#pragma unroll
  for (int d = 0; d < HD_; ++d) acc[d] = 0.f;
  float m = -1e30f, l = 0.f;
  __shared__ float Ks[64][HD_];
  __shared__ float Vs[64][HD_];
  __shared__ int dk[64];
  for (int kt = 0; kt <= qt; ++kt) {
    __syncthreads();
    const float* kp = k_buf + ((size_t)bh * T_ + kt * 64) * HD_;
    const float* vp = v_buf + ((size_t)bh * T_ + kt * 64) * HD_;
#pragma unroll
    for (int i = 0; i < 16; ++i) {
      const int e = lane + (i << 6);
      const int r = e >> 4, c4 = (e & 15) << 2;
      *(float4*)&Ks[r][c4] = *(const float4*)(kp + r * HD_ + c4);
      *(float4*)&Vs[r][c4] = *(const float4*)(vp + r * HD_ + c4);
    }
    dk[lane] = docs[kt * 64 + lane];
    __syncthreads();
#pragma unroll 1
    for (int j0 = 0; j0 < 64; j0 += 16) {
      float S[16];
#pragma unroll
      for (int j = 0; j < 16; ++j) {
        const int kj = j0 + j;
        float s = 0.f;
#pragma unroll
        for (int d = 0; d < HD_; ++d) s = fmaf(q[d], Ks[kj][d], s);
        const int kpos = kt * 64 + kj;
        const bool valid = (kpos <= qpos) && (dk[kj] == docq);
        S[j] = valid ? s * scale : -3.0e38f;
      }
      float cmax = S[0];
#pragma unroll
      for (int j = 1; j < 16; ++j) cmax = fmaxf(cmax, S[j]);
      const float mn = fmaxf(m, cmax);
      const float sc = __expf(m - mn);
      float p[16], ps = 0.f;
#pragma unroll
      for (int j = 0; j < 16; ++j) { p[j] = __expf(S[j] - mn); ps += p[j]; }
      l = fmaf(l, sc, ps);
#pragma unroll
      for (int d = 0; d < HD_; ++d) acc[d] *= sc;
#pragma unroll
      for (int j = 0; j < 16; ++j) {
#pragma unroll
        for (int d = 0; d < HD_; ++d)
          acc[d] = fmaf(p[j], Vs[j0 + j][d], acc[d]);
      }
      m = mn;
    }
  }
  const float gate = attn_gate[(b * T_ + qpos) * H_ + h];
  const float inv = gate / l;
  float* yp = y_buf + (size_t)(b * T_ + qpos) * D_ + h * HD_;
#pragma unroll
  for (int d = 0; d < HD_; d += 4) {
    float4 o;
    o.x = acc[d] * inv; o.y = acc[d + 1] * inv;
    o.z = acc[d + 2] * inv; o.w = acc[d + 3] * inv;
    *(float4*)(yp + d) = o;
  }
}

extern "C" void kernel_launch(void* const* d_in, const int* in_sizes, int n_in,
                              void* d_out, int out_size, void* d_ws, size_t ws_size,
                              hipStream_t stream) {
  const float* x     = (const float*)d_in[0];
  const float* ve    = (const float*)d_in[1];
  const float* lam   = (const float*)d_in[2];
  const float* cosb  = (const float*)d_in[3];
  const float* sinb  = (const float*)d_in[4];
  const float* qkvo  = (const float*)d_in[5];
  const float* agw   = (const float*)d_in[6];
  const float* vgw   = (const float*)d_in[7];
  const float* ascl  = (const float*)d_in[8];
  const int*   docs  = (const int*)d_in[9];
  float* out = (float*)d_out;
  float* ws  = (float*)d_ws;

  const size_t BT = (size_t)B_ * T_;                 // 4096
  float* qkv_raw = ws;                               // BT*3072
  float* q_buf   = qkv_raw + BT * 3 * D_;            // BT*1024 (B,H,T,HD)
  float* k_tmp   = q_buf + BT * D_;
  float* k_buf   = k_tmp + BT * D_;
  float* v_buf   = k_buf + BT * D_;
  float* attn_gate = v_buf + BT * D_;                // BT*H
  float* ve_gate2  = attn_gate + BT * H_;            // BT*H
  float* y_buf   = qkv_raw;                          // alias: qkv_raw dead after post_kernel

  // 1) QKV projection: (4096 x 3072) = x @ (lam0*Wqkv)^T
  gemm_xwT<<<dim3(3 * D_ / BN, BT / BM), 256, 0, stream>>>(
      x, qkvo, qkv_raw, (int)BT, 3 * D_, D_, lam, 0);

  // 2) gates
  gates_kernel<<<(B_ * T_ * H_) / 4, 256, 0, stream>>>(x, agw, vgw, attn_gate, ve_gate2);

  // 3) rmsnorm + rotary + v-augment
  post_kernel<<<(B_ * T_ * H_) / 4, 256, 0, stream>>>(
      qkv_raw, ve, cosb, sinb, ve_gate2, q_buf, k_tmp, v_buf);

  // 4) key channel offset
  koffset_kernel<<<(B_ * H_ * T_ * HD_) / 256, 256, 0, stream>>>(k_tmp, k_buf);

  // 5) doc-masked causal flash attention (+gate), writes y in (B,T,D)
  attn_kernel<<<dim3(T_ / 64, B_ * H_), 64, 0, stream>>>(
      q_buf, k_buf, v_buf, attn_gate, docs, ascl, y_buf);

  // 6) output projection: (4096 x 1024) = y @ (lam1*Wo)^T
  gemm_xwT<<<dim3(D_ / BN, BT / BM), 256, 0, stream>>>(
      y_buf, qkvo + (size_t)3 * D_ * D_, out, (int)BT, D_, D_, lam, 1);
}

// Round 2
// 1164.246 us; speedup vs baseline: 8.2206x; 8.2206x over previous
//
#include <hip/hip_runtime.h>
#include <math.h>

#define B_ 2
#define T_ 2048
#define D_ 1024
#define H_ 16
#define HD_ 64
#define EPS_ 1.1920929e-07f
#define VE_SCALE_ 2.0f

#define BM 64
#define BN 64
#define BKK 16

// C[M,N] = scale * A[M,K] @ W[N,K]^T   (both row-major, K contiguous)
__global__ __launch_bounds__(256) void gemm_xwT(
    const float* __restrict__ A, const float* __restrict__ W,
    float* __restrict__ C, int M, int N, int K,
    const float* __restrict__ lam, int li)
{
  const float scale = lam[li];
  __shared__ float As[BKK][BM + 4];
  __shared__ float Bs[BKK][BN + 4];
  const int tid = threadIdx.x;
  const int tx = tid & 15, ty = tid >> 4;
  const int row0 = blockIdx.y * BM, col0 = blockIdx.x * BN;
  const int lr = tid >> 2;          // 0..63
  const int lk = (tid & 3) << 2;    // 0,4,8,12
  const float* Ap = A + (size_t)(row0 + lr) * K + lk;
  const float* Wp = W + (size_t)(col0 + lr) * K + lk;
  float acc[4][4] = {};
  for (int k0 = 0; k0 < K; k0 += BKK) {
    const float4 av = *(const float4*)(Ap + k0);
    const float4 bv = *(const float4*)(Wp + k0);
    __syncthreads();
    As[lk + 0][lr] = av.x; As[lk + 1][lr] = av.y;
    As[lk + 2][lr] = av.z; As[lk + 3][lr] = av.w;
    Bs[lk + 0][lr] = bv.x; Bs[lk + 1][lr] = bv.y;
    Bs[lk + 2][lr] = bv.z; Bs[lk + 3][lr] = bv.w;
    __syncthreads();
#pragma unroll
    for (int kk = 0; kk < BKK; ++kk) {
      const float4 a4 = *(const float4*)&As[kk][ty << 2];
      const float4 b4 = *(const float4*)&Bs[kk][tx << 2];
      const float a[4] = {a4.x, a4.y, a4.z, a4.w};
      const float b[4] = {b4.x, b4.y, b4.z, b4.w};
#pragma unroll
      for (int i = 0; i < 4; ++i)
#pragma unroll
        for (int j = 0; j < 4; ++j)
          acc[i][j] = fmaf(a[i], b[j], acc[i][j]);
    }
  }
#pragma unroll
  for (int i = 0; i < 4; ++i) {
    float4 o;
    o.x = acc[i][0] * scale; o.y = acc[i][1] * scale;
    o.z = acc[i][2] * scale; o.w = acc[i][3] * scale;
    *(float4*)&C[(size_t)(row0 + (ty << 2) + i) * N + col0 + (tx << 2)] = o;
  }
}

// one wave per (b,t,h): both sigmoid gates
__global__ __launch_bounds__(256) void gates_kernel(
    const float* __restrict__ x, const float* __restrict__ agw,
    const float* __restrict__ vgw, float* __restrict__ attn_gate,
    float* __restrict__ ve_gate2)
{
  const int wid = (blockIdx.x * blockDim.x + threadIdx.x) >> 6;
  const int lane = threadIdx.x & 63;
  const int h = wid & (H_ - 1);
  const int t = (wid >> 4) & (T_ - 1);
  const int b = wid >> 15;
  const float* xp = x + (size_t)(b * T_ + t) * D_;
  const float* ap = agw + (size_t)h * D_;
  const float* vp = vgw + (size_t)h * D_;
  float sa = 0.f, sv = 0.f;
#pragma unroll
  for (int i = 0; i < D_ / 64; ++i) {
    const float xv = xp[lane + (i << 6)];
    sa = fmaf(xv, ap[lane + (i << 6)], sa);
    sv = fmaf(xv, vp[lane + (i << 6)], sv);
  }
#pragma unroll
  for (int off = 32; off > 0; off >>= 1) {
    sa += __shfl_down(sa, off);
    sv += __shfl_down(sv, off);
  }
  if (lane == 0) {
    const int idx = (b * T_ + t) * H_ + h;
    attn_gate[idx] = 1.f / (1.f + __expf(-sa));
    ve_gate2[idx] = VE_SCALE_ / (1.f + __expf(-sv));
  }
}

// one wave per (b,t,h): rmsnorm + rotary for q,k ; v += ve_gate*ve
// writes q_buf/k_tmp/v_buf in (B,H,T,HD) layout
__global__ __launch_bounds__(256) void post_kernel(
    const float* __restrict__ qkv_raw, const float* __restrict__ ve,
    const float* __restrict__ cosb, const float* __restrict__ sinb,
    const float* __restrict__ ve_gate2,
    float* __restrict__ q_buf, float* __restrict__ k_tmp,
    float* __restrict__ v_buf)
{
  const int wid = (blockIdx.x * blockDim.x + threadIdx.x) >> 6;
  const int lane = threadIdx.x & 63;
  const int h = wid & (H_ - 1);
  const int t = (wid >> 4) & (T_ - 1);
  const int b = wid >> 15;
  const size_t row = (size_t)(b * T_ + t) * (3 * D_);
  const float qraw = qkv_raw[row + h * HD_ + lane];
  const float kraw = qkv_raw[row + D_ + h * HD_ + lane];
  const float vraw = qkv_raw[row + 2 * D_ + h * HD_ + lane];
  const float c = cosb[t * (HD_ / 2) + (lane & 31)];
  const float s = sinb[t * (HD_ / 2) + (lane & 31)];

  float ssq = qraw * qraw;
  float ssk = kraw * kraw;
#pragma unroll
  for (int off = 32; off > 0; off >>= 1) {
    ssq += __shfl_xor(ssq, off);
    ssk += __shfl_xor(ssk, off);
  }
  const float qn = qraw * rsqrtf(ssq * (1.f / 64.f) + EPS_);
  const float kn = kraw * rsqrtf(ssk * (1.f / 64.f) + EPS_);
  const float qpartner = __shfl_xor(qn, 32);
  const float kpartner = __shfl_xor(kn, 32);
  const float qo = (lane < 32) ? fmaf(qn, c, qpartner * s)
                               : fmaf(qn, c, -qpartner * s);
  const float ko = (lane < 32) ? fmaf(kn, c, kpartner * s)
                               : fmaf(kn, c, -kpartner * s);
  const int bh = b * H_ + h;
  q_buf[((size_t)bh * T_ + t) * HD_ + lane] = qo;
  k_tmp[((size_t)bh * T_ + t) * HD_ + lane] = ko;
  const float g = ve_gate2[(b * T_ + t) * H_ + h];
  const float vv = fmaf(g, ve[(size_t)(b * T_ + t) * D_ + h * HD_ + lane], vraw);
  v_buf[((size_t)bh * T_ + t) * HD_ + lane] = vv;
}

// KEY_OFFSET: channels [16,32) and [48,64) come from t-1 (t>0)
__global__ __launch_bounds__(256) void koffset_kernel(
    const float* __restrict__ k_tmp, float* __restrict__ k_buf)
{
  const int idx = blockIdx.x * 256 + threadIdx.x;  // < B*H*T*HD
  const int d = idx & 63;
  const int t = (idx >> 6) & (T_ - 1);
  const int bh = idx >> 17;
  const bool off = ((d >= 16) & (d < 32)) | (d >= 48);
  const int ts = (off && t > 0) ? t - 1 : t;
  k_buf[idx] = k_tmp[((size_t)bh * T_ + ts) * HD_ + d];
}

// Flash attention, spill-free: 256 threads = 4 waves per block.
// Thread = (q-row r = tid>>2, d-quarter part = tid&3): owns q[16], acc[16].
// Score dot reduced across the 4 lanes of a row via shfl_xor(1,2).
// Workload balancing: block px processes q-tiles {px, 31-px} -> 33 kv-tiles each.
__global__ __launch_bounds__(256) void attn_kernel(
    const float* __restrict__ q_buf, const float* __restrict__ k_buf,
    const float* __restrict__ v_buf, const float* __restrict__ attn_gate,
    const int* __restrict__ docs, const float* __restrict__ scale_ptr,
    float* __restrict__ y_buf)
{
  const int px = blockIdx.x;         // 0..15
  const int bh = blockIdx.y;         // 0..31
  const int b = bh >> 4, h = bh & 15;
  const int tid = threadIdx.x;
  const int qr = tid >> 2;           // 0..63
  const int d0 = (tid & 3) << 4;     // 0,16,32,48
  const float scale = scale_ptr[0];
  __shared__ float Ks[64][HD_];
  __shared__ float Vs[64][HD_];
  __shared__ int dk[64];

#pragma unroll 1
  for (int half = 0; half < 2; ++half) {
    const int qt = half ? (31 - px) : px;
    const int qpos = qt * 64 + qr;
    const int docq = docs[qpos];
    float q[16];
    {
      const float* qp = q_buf + ((size_t)bh * T_ + qpos) * HD_ + d0;
#pragma unroll
      for (int i = 0; i < 16; i += 4) {
        const float4 v4 = *(const float4*)(qp + i);
        q[i] = v4.x; q[i + 1] = v4.y; q[i + 2] = v4.z; q[i + 3] = v4.w;
      }
    }
    float acc[16];
#pragma unroll
    for (int i = 0; i < 16; ++i) acc[i] = 0.f;
    float m = -1e30f, l = 0.f;

#pragma unroll 1
    for (int kt = 0; kt <= qt; ++kt) {
      __syncthreads();  // previous tile fully consumed
      {
        const float* kp = k_buf + ((size_t)bh * T_ + kt * 64) * HD_;
        const float* vp = v_buf + ((size_t)bh * T_ + kt * 64) * HD_;
#pragma unroll
        for (int i = 0; i < 4; ++i) {
          const int e = tid + (i << 8);          // 0..1023 float4 slots
          const int r = e >> 4, c = (e & 15) << 2;
          *(float4*)&Ks[r][c] = *(const float4*)(kp + r * HD_ + c);
          *(float4*)&Vs[r][c] = *(const float4*)(vp + r * HD_ + c);
        }
        if (tid < 64) dk[tid] = docs[kt * 64 + tid];
      }
      __syncthreads();
      const bool diag = (kt == qt);
#pragma unroll 1
      for (int j0 = 0; j0 < 64; j0 += 16) {
        float S[16];
#pragma unroll
        for (int j = 0; j < 16; ++j) {
          const int kj = j0 + j;
          float s = 0.f;
#pragma unroll
          for (int ii = 0; ii < 4; ++ii) {
            const float4 k4 = *(const float4*)&Ks[kj][d0 + (ii << 2)];
            s = fmaf(q[(ii << 2) + 0], k4.x, s);
            s = fmaf(q[(ii << 2) + 1], k4.y, s);
            s = fmaf(q[(ii << 2) + 2], k4.z, s);
            s = fmaf(q[(ii << 2) + 3], k4.w, s);
          }
          s += __shfl_xor(s, 1);
          s += __shfl_xor(s, 2);
          const bool valid = (dk[kj] == docq) && (!diag || (kt * 64 + kj) <= qpos);
          S[j] = valid ? s * scale : -3.0e38f;
        }
        float cmax = S[0];
#pragma unroll
        for (int j = 1; j < 16; ++j) cmax = fmaxf(cmax, S[j]);
        const float mn = fmaxf(m, cmax);
        const float sc = __expf(m - mn);
        float ps = 0.f;
#pragma unroll
        for (int j = 0; j < 16; ++j) { S[j] = __expf(S[j] - mn); ps += S[j]; }
        l = fmaf(l, sc, ps);
#pragma unroll
        for (int i = 0; i < 16; ++i) acc[i] *= sc;
#pragma unroll
        for (int j = 0; j < 16; ++j) {
#pragma unroll
          for (int ii = 0; ii < 4; ++ii) {
            const float4 v4 = *(const float4*)&Vs[j0 + j][d0 + (ii << 2)];
            acc[(ii << 2) + 0] = fmaf(S[j], v4.x, acc[(ii << 2) + 0]);
            acc[(ii << 2) + 1] = fmaf(S[j], v4.y, acc[(ii << 2) + 1]);
            acc[(ii << 2) + 2] = fmaf(S[j], v4.z, acc[(ii << 2) + 2]);
            acc[(ii << 2) + 3] = fmaf(S[j], v4.w, acc[(ii << 2) + 3]);
          }
        }
        m = mn;
      }
    }
    const float gate = attn_gate[(b * T_ + qpos) * H_ + h];
    const float inv = gate / l;
    float* yp = y_buf + (size_t)(b * T_ + qpos) * D_ + h * HD_ + d0;
#pragma unroll
    for (int i = 0; i < 16; i += 4) {
      float4 o;
      o.x = acc[i] * inv; o.y = acc[i + 1] * inv;
      o.z = acc[i + 2] * inv; o.w = acc[i + 3] * inv;
      *(float4*)(yp + i) = o;
    }
  }
}

extern "C" void kernel_launch(void* const* d_in, const int* in_sizes, int n_in,
                              void* d_out, int out_size, void* d_ws, size_t ws_size,
                              hipStream_t stream) {
  const float* x     = (const float*)d_in[0];
  const float* ve    = (const float*)d_in[1];
  const float* lam   = (const float*)d_in[2];
  const float* cosb  = (const float*)d_in[3];
  const float* sinb  = (const float*)d_in[4];
  const float* qkvo  = (const float*)d_in[5];
  const float* agw   = (const float*)d_in[6];
  const float* vgw   = (const float*)d_in[7];
  const float* ascl  = (const float*)d_in[8];
  const int*   docs  = (const int*)d_in[9];
  float* out = (float*)d_out;
  float* ws  = (float*)d_ws;

  const size_t BT = (size_t)B_ * T_;                 // 4096
  float* qkv_raw = ws;                               // BT*3072
  float* q_buf   = qkv_raw + BT * 3 * D_;            // BT*1024 (B,H,T,HD)
  float* k_tmp   = q_buf + BT * D_;
  float* k_buf   = k_tmp + BT * D_;
  float* v_buf   = k_buf + BT * D_;
  float* attn_gate = v_buf + BT * D_;                // BT*H
  float* ve_gate2  = attn_gate + BT * H_;            // BT*H
  float* y_buf   = qkv_raw;                          // alias: qkv_raw dead after post_kernel

  // 1) QKV projection: (4096 x 3072) = x @ (lam0*Wqkv)^T
  gemm_xwT<<<dim3(3 * D_ / BN, BT / BM), 256, 0, stream>>>(
      x, qkvo, qkv_raw, (int)BT, 3 * D_, D_, lam, 0);

  // 2) gates
  gates_kernel<<<(B_ * T_ * H_) / 4, 256, 0, stream>>>(x, agw, vgw, attn_gate, ve_gate2);

  // 3) rmsnorm + rotary + v-augment
  post_kernel<<<(B_ * T_ * H_) / 4, 256, 0, stream>>>(
      qkv_raw, ve, cosb, sinb, ve_gate2, q_buf, k_tmp, v_buf);

  // 4) key channel offset
  koffset_kernel<<<(B_ * H_ * T_ * HD_) / 256, 256, 0, stream>>>(k_tmp, k_buf);

  // 5) doc-masked causal flash attention (+gate), writes y in (B,T,D)
  //    block px handles q-tiles {px, 31-px} -> uniform 33 kv-tiles/block
  attn_kernel<<<dim3(16, B_ * H_), 256, 0, stream>>>(
      q_buf, k_buf, v_buf, attn_gate, docs, ascl, y_buf);

  // 6) output projection: (4096 x 1024) = y @ (lam1*Wo)^T
  gemm_xwT<<<dim3(D_ / BN, BT / BM), 256, 0, stream>>>(
      y_buf, qkvo + (size_t)3 * D_ * D_, out, (int)BT, D_, D_, lam, 1);
}

// Round 3
// 207.127 us; speedup vs baseline: 46.2073x; 5.6209x over previous
//
#include <hip/hip_runtime.h>
#include <math.h>

#define B_ 2
#define T_ 2048
#define D_ 1024
#define H_ 16
#define HD_ 64
#define EPS_ 1.1920929e-07f
#define VE_SCALE_ 2.0f

typedef __bf16 bf16_t;
typedef __bf16 bf16x4 __attribute__((ext_vector_type(4)));
typedef __bf16 bf16x8 __attribute__((ext_vector_type(8)));
typedef float f32x4 __attribute__((ext_vector_type(4)));

__device__ const f32x4 F4ZERO = {0.f, 0.f, 0.f, 0.f};

// ---------------- cast f32 -> bf16 (vectorized, 4/thread) ----------------
__global__ __launch_bounds__(256) void cast_bf16(
    const float* __restrict__ in, bf16_t* __restrict__ out, int n4)
{
  const int i = blockIdx.x * 256 + threadIdx.x;
  if (i >= n4) return;
  const float4 v = ((const float4*)in)[i];
  bf16x4 o = {(bf16_t)v.x, (bf16_t)v.y, (bf16_t)v.z, (bf16_t)v.w};
  ((bf16x4*)out)[i] = o;
}

// ---------------- bf16 MFMA GEMM: C[M,N] = scale * A @ W^T ----------------
// 128x128 tile, BK=32, 4 waves (2x2 of 64x64), 16x16x32 MFMA, f32 accum.
// LDS rows padded to 40 bf16 (80B) -> optimal 8-lane/bank-window b128 access.
__global__ __launch_bounds__(256) void gemm_bf16(
    const bf16_t* __restrict__ A, const bf16_t* __restrict__ W,
    float* __restrict__ C, int M, int N, int K,
    const float* __restrict__ lam, int li)
{
  const float scale = lam[li];
  __shared__ bf16_t As[128][40];
  __shared__ bf16_t Bs[128][40];
  const int tid = threadIdx.x;
  const int lane = tid & 63;
  const int w = tid >> 6;
  const int lr = lane & 15, lg = lane >> 4;
  const int wr = w >> 1, wc = w & 1;
  const int row0 = blockIdx.y * 128, col0 = blockIdx.x * 128;
  const int srow = tid >> 2;          // 0..63
  const int scol = (tid & 3) << 3;    // 0,8,16,24
  const bf16_t* Abase = A + (size_t)(row0 + srow) * K + scol;
  const bf16_t* Wbase = W + (size_t)(col0 + srow) * K + scol;
  const size_t half = (size_t)64 * K;

  f32x4 acc[4][4];
#pragma unroll
  for (int i = 0; i < 4; ++i)
#pragma unroll
    for (int j = 0; j < 4; ++j) acc[i][j] = F4ZERO;

  bf16x8 ra0 = *(const bf16x8*)(Abase);
  bf16x8 ra1 = *(const bf16x8*)(Abase + half);
  bf16x8 rb0 = *(const bf16x8*)(Wbase);
  bf16x8 rb1 = *(const bf16x8*)(Wbase + half);

  for (int k0 = 0; k0 < K; k0 += 32) {
    __syncthreads();
    *(bf16x8*)&As[srow][scol] = ra0;
    *(bf16x8*)&As[64 + srow][scol] = ra1;
    *(bf16x8*)&Bs[srow][scol] = rb0;
    *(bf16x8*)&Bs[64 + srow][scol] = rb1;
    __syncthreads();
    const int kn = k0 + 32;
    if (kn < K) {  // prefetch next K-tile while computing this one
      ra0 = *(const bf16x8*)(Abase + kn);
      ra1 = *(const bf16x8*)(Abase + half + kn);
      rb0 = *(const bf16x8*)(Wbase + kn);
      rb1 = *(const bf16x8*)(Wbase + half + kn);
    }
    bf16x8 af[4], bfr[4];
#pragma unroll
    for (int fm = 0; fm < 4; ++fm)
      af[fm] = *(const bf16x8*)&As[wr * 64 + fm * 16 + lr][lg * 8];
#pragma unroll
    for (int fn = 0; fn < 4; ++fn)
      bfr[fn] = *(const bf16x8*)&Bs[wc * 64 + fn * 16 + lr][lg * 8];
#pragma unroll
    for (int fm = 0; fm < 4; ++fm)
#pragma unroll
      for (int fn = 0; fn < 4; ++fn)
        acc[fm][fn] = __builtin_amdgcn_mfma_f32_16x16x32_bf16(
            af[fm], bfr[fn], acc[fm][fn], 0, 0, 0);
  }
  // epilogue: C/D layout col=lane&15, row=(lane>>4)*4+reg  [m89]
#pragma unroll
  for (int fm = 0; fm < 4; ++fm)
#pragma unroll
    for (int fn = 0; fn < 4; ++fn)
#pragma unroll
      for (int r = 0; r < 4; ++r) {
        const int row = row0 + wr * 64 + fm * 16 + lg * 4 + r;
        const int col = col0 + wc * 64 + fn * 16 + lr;
        C[(size_t)row * N + col] = acc[fm][fn][r] * scale;
      }
}

// ---------------- gates: one wave per (b,t,h) ----------------
__global__ __launch_bounds__(256) void gates_kernel(
    const float* __restrict__ x, const float* __restrict__ agw,
    const float* __restrict__ vgw, float* __restrict__ attn_gate,
    float* __restrict__ ve_gate2)
{
  const int wid = (blockIdx.x * blockDim.x + threadIdx.x) >> 6;
  const int lane = threadIdx.x & 63;
  const int h = wid & (H_ - 1);
  const int t = (wid >> 4) & (T_ - 1);
  const int b = wid >> 15;
  const float* xp = x + (size_t)(b * T_ + t) * D_;
  const float* ap = agw + (size_t)h * D_;
  const float* vp = vgw + (size_t)h * D_;
  float sa = 0.f, sv = 0.f;
#pragma unroll
  for (int i = 0; i < D_ / 64; ++i) {
    const float xv = xp[lane + (i << 6)];
    sa = fmaf(xv, ap[lane + (i << 6)], sa);
    sv = fmaf(xv, vp[lane + (i << 6)], sv);
  }
#pragma unroll
  for (int off = 32; off > 0; off >>= 1) {
    sa += __shfl_down(sa, off);
    sv += __shfl_down(sv, off);
  }
  if (lane == 0) {
    const int idx = (b * T_ + t) * H_ + h;
    attn_gate[idx] = 1.f / (1.f + __expf(-sa));
    ve_gate2[idx] = VE_SCALE_ / (1.f + __expf(-sv));
  }
}

// ---------------- rmsnorm + rotary + v-augment, bf16 out ----------------
__global__ __launch_bounds__(256) void post_kernel(
    const float* __restrict__ qkv_raw, const float* __restrict__ ve,
    const float* __restrict__ cosb, const float* __restrict__ sinb,
    const float* __restrict__ ve_gate2,
    bf16_t* __restrict__ q_bf, bf16_t* __restrict__ k_bf,
    bf16_t* __restrict__ v_bf)
{
  const int wid = (blockIdx.x * blockDim.x + threadIdx.x) >> 6;
  const int lane = threadIdx.x & 63;
  const int h = wid & (H_ - 1);
  const int t = (wid >> 4) & (T_ - 1);
  const int b = wid >> 15;
  const size_t row = (size_t)(b * T_ + t) * (3 * D_);
  const float qraw = qkv_raw[row + h * HD_ + lane];
  const float kraw = qkv_raw[row + D_ + h * HD_ + lane];
  const float vraw = qkv_raw[row + 2 * D_ + h * HD_ + lane];
  const float c = cosb[t * (HD_ / 2) + (lane & 31)];
  const float s = sinb[t * (HD_ / 2) + (lane & 31)];

  float ssq = qraw * qraw;
  float ssk = kraw * kraw;
#pragma unroll
  for (int off = 32; off > 0; off >>= 1) {
    ssq += __shfl_xor(ssq, off);
    ssk += __shfl_xor(ssk, off);
  }
  const float qn = qraw * rsqrtf(ssq * (1.f / 64.f) + EPS_);
  const float kn = kraw * rsqrtf(ssk * (1.f / 64.f) + EPS_);
  const float qpartner = __shfl_xor(qn, 32);
  const float kpartner = __shfl_xor(kn, 32);
  const float qo = (lane < 32) ? fmaf(qn, c, qpartner * s)
                               : fmaf(qn, c, -qpartner * s);
  const float ko = (lane < 32) ? fmaf(kn, c, kpartner * s)
                               : fmaf(kn, c, -kpartner * s);
  const int bh = b * H_ + h;
  const size_t oidx = ((size_t)bh * T_ + t) * HD_ + lane;
  q_bf[oidx] = (bf16_t)qo;
  k_bf[oidx] = (bf16_t)ko;
  const float g = ve_gate2[(b * T_ + t) * H_ + h];
  const float vv = fmaf(g, ve[(size_t)(b * T_ + t) * D_ + h * HD_ + lane], vraw);
  v_bf[oidx] = (bf16_t)vv;
}

// ---------------- MFMA flash attention ----------------
// Block = 4 waves; wave w owns q-rows [qt*64 + w*16, +16). Per 64-key tile:
// K staged row-major (pad 72) with KEY_OFFSET fused (chunks with c8&16 read
// row t-1); V staged transposed Vt[d][k]; S via 8 MFMA (C-layout); online
// softmax with shfl over the 16-lane col groups; P -> bf16 LDS; PV via 8 MFMA.
__global__ __launch_bounds__(256) void attn_mfma(
    const bf16_t* __restrict__ q_buf, const bf16_t* __restrict__ k_tmp,
    const bf16_t* __restrict__ v_buf, const float* __restrict__ attn_gate,
    const int* __restrict__ docs, const float* __restrict__ scale_ptr,
    bf16_t* __restrict__ y_buf)
{
  const int px = blockIdx.x, bh = blockIdx.y;
  const int b = bh >> 4, h = bh & 15;
  const int tid = threadIdx.x;
  const int w = tid >> 6, lane = tid & 63;
  const int lr = lane & 15, lg = lane >> 4;
  const float scale = scale_ptr[0];
  __shared__ bf16_t Ks[64][72];
  __shared__ bf16_t Vt[64][72];
  __shared__ bf16_t Ps[64][72];
  __shared__ int dk[64];

#pragma unroll 1
  for (int hf = 0; hf < 2; ++hf) {
    const int qt = hf ? (31 - px) : px;
    // Q a-frags hoisted (A-frag: row = lane&15, k = (lane>>4)*8+j)
    const bf16_t* qp = q_buf + ((size_t)bh * T_ + qt * 64 + w * 16 + lr) * HD_;
    const bf16x8 aq0 = *(const bf16x8*)(qp + lg * 8);
    const bf16x8 aq1 = *(const bf16x8*)(qp + 32 + lg * 8);
    int qpos_r[4], docq_r[4];
#pragma unroll
    for (int r = 0; r < 4; ++r) {
      qpos_r[r] = qt * 64 + w * 16 + lg * 4 + r;
      docq_r[r] = docs[qpos_r[r]];
    }
    f32x4 acc[4];
#pragma unroll
    for (int fn = 0; fn < 4; ++fn) acc[fn] = F4ZERO;
    float m[4] = {-1e30f, -1e30f, -1e30f, -1e30f};
    float l[4] = {0.f, 0.f, 0.f, 0.f};

#pragma unroll 1
    for (int kt = 0; kt <= qt; ++kt) {
      __syncthreads();
#pragma unroll
      for (int i = 0; i < 2; ++i) {
        const int idx = i * 256 + tid;
        // K staging (fused key-offset: channels [16,32)|[48,64) from t-1)
        const int krow = idx >> 3;
        const int c8 = (idx & 7) << 3;
        const int gk = kt * 64 + krow;
        const int gks = (((c8 & 16) != 0) && gk > 0) ? gk - 1 : gk;
        *(bf16x8*)&Ks[krow][c8] =
            *(const bf16x8*)(k_tmp + ((size_t)bh * T_ + gks) * HD_ + c8);
        // V transpose staging
        const int kpos = idx & 63;
        const int d0 = (idx >> 6) << 3;
        const bf16x8 vv =
            *(const bf16x8*)(v_buf + ((size_t)bh * T_ + kt * 64 + kpos) * HD_ + d0);
#pragma unroll
        for (int j = 0; j < 8; ++j) Vt[d0 + j][kpos] = vv[j];
      }
      if (tid < 64) dk[tid] = docs[kt * 64 + tid];
      __syncthreads();

      // S = Q K^T  (B-frag: col = lane&15 = kpos, k = d contiguous)
      f32x4 s[4];
#pragma unroll
      for (int fn = 0; fn < 4; ++fn) {
        const bf16x8 bk0 = *(const bf16x8*)&Ks[fn * 16 + lr][lg * 8];
        const bf16x8 bk1 = *(const bf16x8*)&Ks[fn * 16 + lr][32 + lg * 8];
        f32x4 z = F4ZERO;
        z = __builtin_amdgcn_mfma_f32_16x16x32_bf16(aq0, bk0, z, 0, 0, 0);
        s[fn] = __builtin_amdgcn_mfma_f32_16x16x32_bf16(aq1, bk1, z, 0, 0, 0);
      }
      // mask + scale (lane holds rows lg*4+r, col fn*16+lr of the 64x64 S)
      const bool strict = (kt < qt);
#pragma unroll
      for (int fn = 0; fn < 4; ++fn) {
        const int kd = dk[fn * 16 + lr];
        const int kp = kt * 64 + fn * 16 + lr;
#pragma unroll
        for (int r = 0; r < 4; ++r) {
          const bool valid = (kd == docq_r[r]) && (strict || kp <= qpos_r[r]);
          s[fn][r] = valid ? s[fn][r] * scale : -3.0e38f;
        }
      }
      // online softmax (row reduce across 16-lane col group) + P write
#pragma unroll
      for (int r = 0; r < 4; ++r) {
        float cm = fmaxf(fmaxf(s[0][r], s[1][r]), fmaxf(s[2][r], s[3][r]));
        cm = fmaxf(cm, __shfl_xor(cm, 1));
        cm = fmaxf(cm, __shfl_xor(cm, 2));
        cm = fmaxf(cm, __shfl_xor(cm, 4));
        cm = fmaxf(cm, __shfl_xor(cm, 8));
        const float mn = fmaxf(m[r], cm);
        const float sc = __expf(m[r] - mn);
        m[r] = mn;
        const float p0 = __expf(s[0][r] - mn);
        const float p1 = __expf(s[1][r] - mn);
        const float p2 = __expf(s[2][r] - mn);
        const float p3 = __expf(s[3][r] - mn);
        float ps = (p0 + p1) + (p2 + p3);
        ps += __shfl_xor(ps, 1);
        ps += __shfl_xor(ps, 2);
        ps += __shfl_xor(ps, 4);
        ps += __shfl_xor(ps, 8);
        l[r] = l[r] * sc + ps;
        acc[0][r] *= sc; acc[1][r] *= sc; acc[2][r] *= sc; acc[3][r] *= sc;
        const int prow = w * 16 + lg * 4 + r;
        Ps[prow][0 + lr]  = (bf16_t)p0;
        Ps[prow][16 + lr] = (bf16_t)p1;
        Ps[prow][32 + lr] = (bf16_t)p2;
        Ps[prow][48 + lr] = (bf16_t)p3;
      }
      // PV: A = P rows (wave-private LDS slice), B = Vt rows (col = d)
      const bf16x8 ap0 = *(const bf16x8*)&Ps[w * 16 + lr][lg * 8];
      const bf16x8 ap1 = *(const bf16x8*)&Ps[w * 16 + lr][32 + lg * 8];
#pragma unroll
      for (int fn = 0; fn < 4; ++fn) {
        const bf16x8 bv0 = *(const bf16x8*)&Vt[fn * 16 + lr][lg * 8];
        const bf16x8 bv1 = *(const bf16x8*)&Vt[fn * 16 + lr][32 + lg * 8];
        acc[fn] = __builtin_amdgcn_mfma_f32_16x16x32_bf16(ap0, bv0, acc[fn], 0, 0, 0);
        acc[fn] = __builtin_amdgcn_mfma_f32_16x16x32_bf16(ap1, bv1, acc[fn], 0, 0, 0);
      }
    }
    // epilogue: gate & normalize, write bf16 y (B,T,D)
#pragma unroll
    for (int r = 0; r < 4; ++r) {
      const float inv = attn_gate[(size_t)(b * T_ + qpos_r[r]) * H_ + h] / l[r];
#pragma unroll
      for (int fn = 0; fn < 4; ++fn)
        y_buf[(size_t)(b * T_ + qpos_r[r]) * D_ + h * HD_ + fn * 16 + lr] =
            (bf16_t)(acc[fn][r] * inv);
    }
  }
}

extern "C" void kernel_launch(void* const* d_in, const int* in_sizes, int n_in,
                              void* d_out, int out_size, void* d_ws, size_t ws_size,
                              hipStream_t stream) {
  const float* x    = (const float*)d_in[0];
  const float* ve   = (const float*)d_in[1];
  const float* lam  = (const float*)d_in[2];
  const float* cosb = (const float*)d_in[3];
  const float* sinb = (const float*)d_in[4];
  const float* qkvo = (const float*)d_in[5];
  const float* agw  = (const float*)d_in[6];
  const float* vgw  = (const float*)d_in[7];
  const float* ascl = (const float*)d_in[8];
  const int*   docs = (const int*)d_in[9];
  float* out = (float*)d_out;

  const size_t BT = (size_t)B_ * T_;  // 4096
  float* cur = (float*)d_ws;
  float* qkv_raw = cur;               cur += BT * 3 * D_;    // f32
  bf16_t* x_bf = (bf16_t*)cur;        cur += BT * D_ / 2;
  bf16_t* w_bf = (bf16_t*)cur;        cur += (size_t)4 * D_ * D_ / 2;
  bf16_t* q_bf = (bf16_t*)cur;        cur += BT * D_ / 2;
  bf16_t* k_bf = (bf16_t*)cur;        cur += BT * D_ / 2;
  bf16_t* v_bf = (bf16_t*)cur;        cur += BT * D_ / 2;
  bf16_t* y_bf = (bf16_t*)cur;        cur += BT * D_ / 2;
  float* attn_gate = cur;             cur += BT * H_;
  float* ve_gate2 = cur;              cur += BT * H_;

  // casts
  const int nx4 = (int)(BT * D_ / 4);
  const int nw4 = (int)((size_t)4 * D_ * D_ / 4);
  cast_bf16<<<(nx4 + 255) / 256, 256, 0, stream>>>(x, x_bf, nx4);
  cast_bf16<<<(nw4 + 255) / 256, 256, 0, stream>>>(qkvo, w_bf, nw4);

  // 1) QKV projection (bf16 MFMA, f32 out)
  gemm_bf16<<<dim3(3 * D_ / 128, BT / 128), 256, 0, stream>>>(
      x_bf, w_bf, qkv_raw, (int)BT, 3 * D_, D_, lam, 0);

  // 2) gates
  gates_kernel<<<(B_ * T_ * H_) / 4, 256, 0, stream>>>(x, agw, vgw, attn_gate, ve_gate2);

  // 3) rmsnorm + rotary + v-augment -> bf16 q/k/v (B,H,T,HD)
  post_kernel<<<(B_ * T_ * H_) / 4, 256, 0, stream>>>(
      qkv_raw, ve, cosb, sinb, ve_gate2, q_bf, k_bf, v_bf);

  // 4) MFMA flash attention (key-offset fused into K staging) -> bf16 y
  attn_mfma<<<dim3(16, B_ * H_), 256, 0, stream>>>(
      q_bf, k_bf, v_bf, attn_gate, docs, ascl, y_bf);

  // 5) output projection (bf16 MFMA, f32 out)
  gemm_bf16<<<dim3(D_ / 128, BT / 128), 256, 0, stream>>>(
      y_bf, w_bf + (size_t)3 * D_ * D_, out, (int)BT, D_, D_, lam, 1);
}

// Round 4
// 154.264 us; speedup vs baseline: 62.0416x; 1.3427x over previous
//
#include <hip/hip_runtime.h>
#include <math.h>

#define B_ 2
#define T_ 2048
#define D_ 1024
#define H_ 16
#define HD_ 64
#define EPS_ 1.1920929e-07f
#define VE_SCALE_ 2.0f

typedef __bf16 bf16_t;
typedef __bf16 bf16x4 __attribute__((ext_vector_type(4)));
typedef __bf16 bf16x8 __attribute__((ext_vector_type(8)));
typedef float f32x4 __attribute__((ext_vector_type(4)));

__device__ const f32x4 F4ZERO = {0.f, 0.f, 0.f, 0.f};

typedef __attribute__((address_space(1))) const void gvoid_t;
typedef __attribute__((address_space(3))) void lvoid_t;

__device__ __forceinline__ void gl_lds16(const bf16_t* g, bf16_t* l) {
  // async global->LDS, 16B/lane; LDS dest = wave-uniform base + lane*16
  __builtin_amdgcn_global_load_lds((gvoid_t*)g, (lvoid_t*)l, 16, 0, 0);
}

// ---------------- cast f32 -> bf16 (vectorized, 4/thread) ----------------
__global__ __launch_bounds__(256) void cast_bf16(
    const float* __restrict__ in, bf16_t* __restrict__ out, int n4)
{
  const int i = blockIdx.x * 256 + threadIdx.x;
  if (i >= n4) return;
  const float4 v = ((const float4*)in)[i];
  bf16x4 o = {(bf16_t)v.x, (bf16_t)v.y, (bf16_t)v.z, (bf16_t)v.w};
  ((bf16x4*)out)[i] = o;
}

// ---------------- bf16 MFMA GEMM (m97 structure): C = scale * A @ W^T ----
// 128x128 tile, BK=32, 4 waves (2x2 of 64x64), global_load_lds width-16
// staging into linear LDS, 2-barrier K-loop, 16 MFMA/wave/K-step.
__global__ __launch_bounds__(256) void gemm_bf16(
    const bf16_t* __restrict__ A, const bf16_t* __restrict__ W,
    float* __restrict__ C, int M, int N, int K,
    const float* __restrict__ lam, int li)
{
  const float scale = lam[li];
  __shared__ bf16_t As[128][32];
  __shared__ bf16_t Bs[128][32];
  const int tid = threadIdx.x;
  const int lane = tid & 63, w = tid >> 6;
  const int lr = lane & 15, lg = lane >> 4;
  const int wr = w >> 1, wc = w & 1;
  const int row0 = blockIdx.y * 128, col0 = blockIdx.x * 128;
  // staging: wave w covers tile rows [w*32, w*32+32); instr i covers 16 rows
  const int srow = w * 32 + (lane >> 2);
  const int scol = (lane & 3) * 8;
  const bf16_t* Ag = A + (size_t)(row0 + srow) * K + scol;
  const bf16_t* Wg = W + (size_t)(col0 + srow) * K + scol;
  bf16_t* AsB0 = &As[w * 32][0];
  bf16_t* AsB1 = &As[w * 32 + 16][0];
  bf16_t* BsB0 = &Bs[w * 32][0];
  bf16_t* BsB1 = &Bs[w * 32 + 16][0];
  const size_t r16 = (size_t)16 * K;

  f32x4 acc[4][4];
#pragma unroll
  for (int i = 0; i < 4; ++i)
#pragma unroll
    for (int j = 0; j < 4; ++j) acc[i][j] = F4ZERO;

  for (int k0 = 0; k0 < K; k0 += 32) {
    __syncthreads();  // previous K-tile fully consumed
    gl_lds16(Ag + k0, AsB0);
    gl_lds16(Ag + r16 + k0, AsB1);
    gl_lds16(Wg + k0, BsB0);
    gl_lds16(Wg + r16 + k0, BsB1);
    __syncthreads();  // drains vmcnt(0): staged data visible

    bf16x8 af[4], bfr[4];
#pragma unroll
    for (int fm = 0; fm < 4; ++fm)
      af[fm] = *(const bf16x8*)&As[wr * 64 + fm * 16 + lr][lg * 8];
#pragma unroll
    for (int fn = 0; fn < 4; ++fn)
      bfr[fn] = *(const bf16x8*)&Bs[wc * 64 + fn * 16 + lr][lg * 8];
#pragma unroll
    for (int fm = 0; fm < 4; ++fm)
#pragma unroll
      for (int fn = 0; fn < 4; ++fn)
        acc[fm][fn] = __builtin_amdgcn_mfma_f32_16x16x32_bf16(
            af[fm], bfr[fn], acc[fm][fn], 0, 0, 0);
  }
  // epilogue: C/D layout col=lane&15, row=(lane>>4)*4+reg  [m89]
#pragma unroll
  for (int fm = 0; fm < 4; ++fm)
#pragma unroll
    for (int fn = 0; fn < 4; ++fn)
#pragma unroll
      for (int r = 0; r < 4; ++r) {
        const int row = row0 + wr * 64 + fm * 16 + lg * 4 + r;
        const int col = col0 + wc * 64 + fn * 16 + lr;
        C[(size_t)row * N + col] = acc[fm][fn][r] * scale;
      }
}

// ---------------- gates: one wave per (b,t,h) ----------------
__global__ __launch_bounds__(256) void gates_kernel(
    const float* __restrict__ x, const float* __restrict__ agw,
    const float* __restrict__ vgw, float* __restrict__ attn_gate,
    float* __restrict__ ve_gate2)
{
  const int wid = (blockIdx.x * blockDim.x + threadIdx.x) >> 6;
  const int lane = threadIdx.x & 63;
  const int h = wid & (H_ - 1);
  const int t = (wid >> 4) & (T_ - 1);
  const int b = wid >> 15;
  const float* xp = x + (size_t)(b * T_ + t) * D_;
  const float* ap = agw + (size_t)h * D_;
  const float* vp = vgw + (size_t)h * D_;
  float sa = 0.f, sv = 0.f;
#pragma unroll
  for (int i = 0; i < D_ / 64; ++i) {
    const float xv = xp[lane + (i << 6)];
    sa = fmaf(xv, ap[lane + (i << 6)], sa);
    sv = fmaf(xv, vp[lane + (i << 6)], sv);
  }
#pragma unroll
  for (int off = 32; off > 0; off >>= 1) {
    sa += __shfl_down(sa, off);
    sv += __shfl_down(sv, off);
  }
  if (lane == 0) {
    const int idx = (b * T_ + t) * H_ + h;
    attn_gate[idx] = 1.f / (1.f + __expf(-sa));
    ve_gate2[idx] = VE_SCALE_ / (1.f + __expf(-sv));
  }
}

// ---------------- rmsnorm + rotary + v-augment, bf16 out ----------------
__global__ __launch_bounds__(256) void post_kernel(
    const float* __restrict__ qkv_raw, const float* __restrict__ ve,
    const float* __restrict__ cosb, const float* __restrict__ sinb,
    const float* __restrict__ ve_gate2,
    bf16_t* __restrict__ q_bf, bf16_t* __restrict__ k_bf,
    bf16_t* __restrict__ v_bf)
{
  const int wid = (blockIdx.x * blockDim.x + threadIdx.x) >> 6;
  const int lane = threadIdx.x & 63;
  const int h = wid & (H_ - 1);
  const int t = (wid >> 4) & (T_ - 1);
  const int b = wid >> 15;
  const size_t row = (size_t)(b * T_ + t) * (3 * D_);
  const float qraw = qkv_raw[row + h * HD_ + lane];
  const float kraw = qkv_raw[row + D_ + h * HD_ + lane];
  const float vraw = qkv_raw[row + 2 * D_ + h * HD_ + lane];
  const float c = cosb[t * (HD_ / 2) + (lane & 31)];
  const float s = sinb[t * (HD_ / 2) + (lane & 31)];

  float ssq = qraw * qraw;
  float ssk = kraw * kraw;
#pragma unroll
  for (int off = 32; off > 0; off >>= 1) {
    ssq += __shfl_xor(ssq, off);
    ssk += __shfl_xor(ssk, off);
  }
  const float qn = qraw * rsqrtf(ssq * (1.f / 64.f) + EPS_);
  const float kn = kraw * rsqrtf(ssk * (1.f / 64.f) + EPS_);
  const float qpartner = __shfl_xor(qn, 32);
  const float kpartner = __shfl_xor(kn, 32);
  const float qo = (lane < 32) ? fmaf(qn, c, qpartner * s)
                               : fmaf(qn, c, -qpartner * s);
  const float ko = (lane < 32) ? fmaf(kn, c, kpartner * s)
                               : fmaf(kn, c, -kpartner * s);
  const int bh = b * H_ + h;
  const size_t oidx = ((size_t)bh * T_ + t) * HD_ + lane;
  q_bf[oidx] = (bf16_t)qo;
  k_bf[oidx] = (bf16_t)ko;
  const float g = ve_gate2[(b * T_ + t) * H_ + h];
  const float vv = fmaf(g, ve[(size_t)(b * T_ + t) * D_ + h * HD_ + lane], vraw);
  v_bf[oidx] = (bf16_t)vv;
}

// ---------------- MFMA flash attention, doc-block-diagonal ----------------
// Grid (32 q-tiles, 32 bh); block = 4 waves, wave w owns q-rows w*16..+16.
// docs sorted => q-tile qt only attends kt in [ktlo, qt] where
// ktlo = first kt with docs[kt*64+63] >= docs[qt*64] (earlier tiles all-masked).
__global__ __launch_bounds__(256) void attn_mfma(
    const bf16_t* __restrict__ q_buf, const bf16_t* __restrict__ k_tmp,
    const bf16_t* __restrict__ v_buf, const float* __restrict__ attn_gate,
    const int* __restrict__ docs, const float* __restrict__ scale_ptr,
    bf16_t* __restrict__ y_buf)
{
  const int qt = blockIdx.x, bh = blockIdx.y;
  const int b = bh >> 4, h = bh & 15;
  const int tid = threadIdx.x;
  const int w = tid >> 6, lane = tid & 63;
  const int lr = lane & 15, lg = lane >> 4;
  const float scale = scale_ptr[0];
  __shared__ bf16_t Ks[64][72];
  __shared__ bf16_t Vt[64][72];
  __shared__ bf16_t Ps[64][72];
  __shared__ int dk[64];

  // doc-range lower bound for this q-tile
  const int dlo = docs[qt * 64];
  const unsigned long long bal =
      __ballot((lane <= qt) && (docs[lane * 64 + 63] >= dlo));
  const int ktlo = __ffsll(bal) - 1;

  // Q a-frags hoisted (A-frag: row = lane&15, k = (lane>>4)*8+j)
  const bf16_t* qp = q_buf + ((size_t)bh * T_ + qt * 64 + w * 16 + lr) * HD_;
  const bf16x8 aq0 = *(const bf16x8*)(qp + lg * 8);
  const bf16x8 aq1 = *(const bf16x8*)(qp + 32 + lg * 8);
  int qpos_r[4], docq_r[4];
#pragma unroll
  for (int r = 0; r < 4; ++r) {
    qpos_r[r] = qt * 64 + w * 16 + lg * 4 + r;
    docq_r[r] = docs[qpos_r[r]];
  }
  f32x4 acc[4];
#pragma unroll
  for (int fn = 0; fn < 4; ++fn) acc[fn] = F4ZERO;
  float m[4] = {-1e30f, -1e30f, -1e30f, -1e30f};
  float l[4] = {0.f, 0.f, 0.f, 0.f};

#pragma unroll 1
  for (int kt = ktlo; kt <= qt; ++kt) {
    __syncthreads();
#pragma unroll
    for (int i = 0; i < 2; ++i) {
      const int idx = i * 256 + tid;
      // K staging (fused key-offset: channels [16,32)|[48,64) from t-1)
      const int krow = idx >> 3;
      const int c8 = (idx & 7) << 3;
      const int gk = kt * 64 + krow;
      const int gks = (((c8 & 16) != 0) && gk > 0) ? gk - 1 : gk;
      *(bf16x8*)&Ks[krow][c8] =
          *(const bf16x8*)(k_tmp + ((size_t)bh * T_ + gks) * HD_ + c8);
      // V transpose staging
      const int kpos = idx & 63;
      const int d0 = (idx >> 6) << 3;
      const bf16x8 vv =
          *(const bf16x8*)(v_buf + ((size_t)bh * T_ + kt * 64 + kpos) * HD_ + d0);
#pragma unroll
      for (int j = 0; j < 8; ++j) Vt[d0 + j][kpos] = vv[j];
    }
    if (tid < 64) dk[tid] = docs[kt * 64 + tid];
    __syncthreads();

    // S = Q K^T  (B-frag: col = lane&15 = kpos, k = d contiguous)
    f32x4 s[4];
#pragma unroll
    for (int fn = 0; fn < 4; ++fn) {
      const bf16x8 bk0 = *(const bf16x8*)&Ks[fn * 16 + lr][lg * 8];
      const bf16x8 bk1 = *(const bf16x8*)&Ks[fn * 16 + lr][32 + lg * 8];
      f32x4 z = F4ZERO;
      z = __builtin_amdgcn_mfma_f32_16x16x32_bf16(aq0, bk0, z, 0, 0, 0);
      s[fn] = __builtin_amdgcn_mfma_f32_16x16x32_bf16(aq1, bk1, z, 0, 0, 0);
    }
    // mask + scale (lane holds rows lg*4+r, col fn*16+lr of the 64x64 S)
    const bool strict = (kt < qt);
#pragma unroll
    for (int fn = 0; fn < 4; ++fn) {
      const int kd = dk[fn * 16 + lr];
      const int kp = kt * 64 + fn * 16 + lr;
#pragma unroll
      for (int r = 0; r < 4; ++r) {
        const bool valid = (kd == docq_r[r]) && (strict || kp <= qpos_r[r]);
        s[fn][r] = valid ? s[fn][r] * scale : -3.0e38f;
      }
    }
    // online softmax (row reduce across 16-lane col group) + P write
#pragma unroll
    for (int r = 0; r < 4; ++r) {
      float cm = fmaxf(fmaxf(s[0][r], s[1][r]), fmaxf(s[2][r], s[3][r]));
      cm = fmaxf(cm, __shfl_xor(cm, 1));
      cm = fmaxf(cm, __shfl_xor(cm, 2));
      cm = fmaxf(cm, __shfl_xor(cm, 4));
      cm = fmaxf(cm, __shfl_xor(cm, 8));
      const float mn = fmaxf(m[r], cm);
      const float sc = __expf(m[r] - mn);
      m[r] = mn;
      const float p0 = __expf(s[0][r] - mn);
      const float p1 = __expf(s[1][r] - mn);
      const float p2 = __expf(s[2][r] - mn);
      const float p3 = __expf(s[3][r] - mn);
      float ps = (p0 + p1) + (p2 + p3);
      ps += __shfl_xor(ps, 1);
      ps += __shfl_xor(ps, 2);
      ps += __shfl_xor(ps, 4);
      ps += __shfl_xor(ps, 8);
      l[r] = l[r] * sc + ps;
      acc[0][r] *= sc; acc[1][r] *= sc; acc[2][r] *= sc; acc[3][r] *= sc;
      const int prow = w * 16 + lg * 4 + r;
      Ps[prow][0 + lr]  = (bf16_t)p0;
      Ps[prow][16 + lr] = (bf16_t)p1;
      Ps[prow][32 + lr] = (bf16_t)p2;
      Ps[prow][48 + lr] = (bf16_t)p3;
    }
    // PV: A = P rows (wave-private LDS slice), B = Vt rows (col = d)
    const bf16x8 ap0 = *(const bf16x8*)&Ps[w * 16 + lr][lg * 8];
    const bf16x8 ap1 = *(const bf16x8*)&Ps[w * 16 + lr][32 + lg * 8];
#pragma unroll
    for (int fn = 0; fn < 4; ++fn) {
      const bf16x8 bv0 = *(const bf16x8*)&Vt[fn * 16 + lr][lg * 8];
      const bf16x8 bv1 = *(const bf16x8*)&Vt[fn * 16 + lr][32 + lg * 8];
      acc[fn] = __builtin_amdgcn_mfma_f32_16x16x32_bf16(ap0, bv0, acc[fn], 0, 0, 0);
      acc[fn] = __builtin_amdgcn_mfma_f32_16x16x32_bf16(ap1, bv1, acc[fn], 0, 0, 0);
    }
  }
  // epilogue: gate & normalize, write bf16 y (B,T,D)
#pragma unroll
  for (int r = 0; r < 4; ++r) {
    const float inv = attn_gate[(size_t)(b * T_ + qpos_r[r]) * H_ + h] / l[r];
#pragma unroll
    for (int fn = 0; fn < 4; ++fn)
      y_buf[(size_t)(b * T_ + qpos_r[r]) * D_ + h * HD_ + fn * 16 + lr] =
          (bf16_t)(acc[fn][r] * inv);
  }
}

extern "C" void kernel_launch(void* const* d_in, const int* in_sizes, int n_in,
                              void* d_out, int out_size, void* d_ws, size_t ws_size,
                              hipStream_t stream) {
  const float* x    = (const float*)d_in[0];
  const float* ve   = (const float*)d_in[1];
  const float* lam  = (const float*)d_in[2];
  const float* cosb = (const float*)d_in[3];
  const float* sinb = (const float*)d_in[4];
  const float* qkvo = (const float*)d_in[5];
  const float* agw  = (const float*)d_in[6];
  const float* vgw  = (const float*)d_in[7];
  const float* ascl = (const float*)d_in[8];
  const int*   docs = (const int*)d_in[9];
  float* out = (float*)d_out;

  const size_t BT = (size_t)B_ * T_;  // 4096
  float* cur = (float*)d_ws;
  float* qkv_raw = cur;               cur += BT * 3 * D_;    // f32
  bf16_t* x_bf = (bf16_t*)cur;        cur += BT * D_ / 2;
  bf16_t* w_bf = (bf16_t*)cur;        cur += (size_t)4 * D_ * D_ / 2;
  bf16_t* q_bf = (bf16_t*)cur;        cur += BT * D_ / 2;
  bf16_t* k_bf = (bf16_t*)cur;        cur += BT * D_ / 2;
  bf16_t* v_bf = (bf16_t*)cur;        cur += BT * D_ / 2;
  bf16_t* y_bf = (bf16_t*)cur;        cur += BT * D_ / 2;
  float* attn_gate = cur;             cur += BT * H_;
  float* ve_gate2 = cur;              cur += BT * H_;

  // casts
  const int nx4 = (int)(BT * D_ / 4);
  const int nw4 = (int)((size_t)4 * D_ * D_ / 4);
  cast_bf16<<<(nx4 + 255) / 256, 256, 0, stream>>>(x, x_bf, nx4);
  cast_bf16<<<(nw4 + 255) / 256, 256, 0, stream>>>(qkvo, w_bf, nw4);

  // 1) QKV projection (bf16 MFMA, f32 out)
  gemm_bf16<<<dim3(3 * D_ / 128, BT / 128), 256, 0, stream>>>(
      x_bf, w_bf, qkv_raw, (int)BT, 3 * D_, D_, lam, 0);

  // 2) gates
  gates_kernel<<<(B_ * T_ * H_) / 4, 256, 0, stream>>>(x, agw, vgw, attn_gate, ve_gate2);

  // 3) rmsnorm + rotary + v-augment -> bf16 q/k/v (B,H,T,HD)
  post_kernel<<<(B_ * T_ * H_) / 4, 256, 0, stream>>>(
      qkv_raw, ve, cosb, sinb, ve_gate2, q_bf, k_bf, v_bf);

  // 4) MFMA flash attention (doc-block-diagonal skip; key-offset fused)
  attn_mfma<<<dim3(T_ / 64, B_ * H_), 256, 0, stream>>>(
      q_bf, k_bf, v_bf, attn_gate, docs, ascl, y_bf);

  // 5) output projection (bf16 MFMA, f32 out)
  gemm_bf16<<<dim3(D_ / 128, BT / 128), 256, 0, stream>>>(
      y_bf, w_bf + (size_t)3 * D_ * D_, out, (int)BT, D_, D_, lam, 1);
}

// Round 6
// 142.067 us; speedup vs baseline: 67.3682x; 1.0859x over previous
//
#include <hip/hip_runtime.h>
#include <math.h>

#define B_ 2
#define T_ 2048
#define D_ 1024
#define H_ 16
#define HD_ 64
#define EPS_ 1.1920929e-07f
#define VE_SCALE_ 2.0f
#define QN_ 3200   // 3072 qkv cols + 16 attn-gate + 16 ve-gate + 96 pad

typedef __bf16 bf16_t;
typedef __bf16 bf16x4 __attribute__((ext_vector_type(4)));
typedef __bf16 bf16x8 __attribute__((ext_vector_type(8)));
typedef float f32x4 __attribute__((ext_vector_type(4)));

__device__ const f32x4 F4ZERO = {0.f, 0.f, 0.f, 0.f};

typedef __attribute__((address_space(1))) const void gvoid_t;
typedef __attribute__((address_space(3))) void lvoid_t;

__device__ __forceinline__ void gl_lds16(const bf16_t* g, bf16_t* l) {
  // async global->LDS, 16B/lane; LDS dest = wave-uniform base + lane*16
  __builtin_amdgcn_global_load_lds((gvoid_t*)g, (lvoid_t*)l, 16, 0, 0);
}

// ---------------- cast f32 -> bf16 (vectorized, 4/thread) ----------------
__global__ __launch_bounds__(256) void cast_bf16(
    const float* __restrict__ in, bf16_t* __restrict__ out, int n4)
{
  const int i = blockIdx.x * 256 + threadIdx.x;
  if (i >= n4) return;
  const float4 v = ((const float4*)in)[i];
  bf16x4 o = {(bf16_t)v.x, (bf16_t)v.y, (bf16_t)v.z, (bf16_t)v.w};
  ((bf16x4*)out)[i] = o;
}

// ---------------- bf16 MFMA GEMM: C = scale * A @ W^T ----------------
// 128x128 tile, BK=64, 4 waves (2x2 of 64x64), global_load_lds width-16
// into linear LDS with pre-swizzled global source (chunk ^= row&7), reads
// apply the same involution. 32 MFMA/wave/K-step, 2 barriers per K-step.
// XCD-swizzled block mapping. Cols >= n_scaled skip the lambda scale.
__global__ __launch_bounds__(256) void gemm_bf16(
    const bf16_t* __restrict__ A, const bf16_t* __restrict__ W,
    void* __restrict__ Cout, int M, int N, int K,
    const float* __restrict__ lam, int li, int n_scaled, int out_bf)
{
  const float scale = lam[li];
  __shared__ bf16_t As[128][64];
  __shared__ bf16_t Bs[128][64];
  const int tid = threadIdx.x;
  const int lane = tid & 63, w = tid >> 6;
  const int lr = lane & 15, lg = lane >> 4;
  const int wr = w >> 1, wc = w & 1;

  // bijective XCD swizzle (grids are multiples of 8 blocks)
  const int nwg = gridDim.x * gridDim.y;
  int bid = blockIdx.y * gridDim.x + blockIdx.x;
  bid = (bid & 7) * (nwg >> 3) + (bid >> 3);
  const int row0 = (bid / gridDim.x) * 128;
  const int col0 = (bid % gridDim.x) * 128;

  // staging map: wave w covers tile rows [w*32, +32); instr i covers 8 rows.
  // lane -> local row rl = lane>>3, chunk c = lane&7; fetch global chunk
  // cg = c ^ rl so that LDS[r][j ^ (r&7)] holds global chunk j.
  const int rl = lane >> 3;
  const int cg = (lane & 7) ^ rl;
  const bf16_t* Ag = A + (size_t)(row0 + w * 32 + rl) * K + cg * 8;
  const bf16_t* Wg = W + (size_t)(col0 + w * 32 + rl) * K + cg * 8;
  bf16_t* AsW = &As[w * 32][0];
  bf16_t* BsW = &Bs[w * 32][0];

  f32x4 acc[4][4];
#pragma unroll
  for (int i = 0; i < 4; ++i)
#pragma unroll
    for (int j = 0; j < 4; ++j) acc[i][j] = F4ZERO;

  const int sA = lr & 7;          // read-side swizzle key (row&7)
  const int c0 = (lg ^ sA) * 8;   // element offset of k-chunk lg
  const int c1 = c0 ^ 32;         // k-chunk lg+4 (chunk ^4 = elem ^32)

  for (int k0 = 0; k0 < K; k0 += 64) {
    __syncthreads();  // previous K-tile fully consumed
#pragma unroll
    for (int i = 0; i < 4; ++i) {
      gl_lds16(Ag + (size_t)(i * 8) * K + k0, AsW + i * 512);
      gl_lds16(Wg + (size_t)(i * 8) * K + k0, BsW + i * 512);
    }
    __syncthreads();  // drains vmcnt(0): staged data visible

    bf16x8 af[4], bfr[4];
#pragma unroll
    for (int fm = 0; fm < 4; ++fm)
      af[fm] = *(const bf16x8*)&As[wr * 64 + fm * 16 + lr][c0];
#pragma unroll
    for (int fn = 0; fn < 4; ++fn)
      bfr[fn] = *(const bf16x8*)&Bs[wc * 64 + fn * 16 + lr][c0];
#pragma unroll
    for (int fm = 0; fm < 4; ++fm)
#pragma unroll
      for (int fn = 0; fn < 4; ++fn)
        acc[fm][fn] = __builtin_amdgcn_mfma_f32_16x16x32_bf16(
            af[fm], bfr[fn], acc[fm][fn], 0, 0, 0);
#pragma unroll
    for (int fm = 0; fm < 4; ++fm)
      af[fm] = *(const bf16x8*)&As[wr * 64 + fm * 16 + lr][c1];
#pragma unroll
    for (int fn = 0; fn < 4; ++fn)
      bfr[fn] = *(const bf16x8*)&Bs[wc * 64 + fn * 16 + lr][c1];
#pragma unroll
    for (int fm = 0; fm < 4; ++fm)
#pragma unroll
      for (int fn = 0; fn < 4; ++fn)
        acc[fm][fn] = __builtin_amdgcn_mfma_f32_16x16x32_bf16(
            af[fm], bfr[fn], acc[fm][fn], 0, 0, 0);
  }
  // epilogue: C/D layout col=lane&15, row=(lane>>4)*4+reg  [m89]
#pragma unroll
  for (int fm = 0; fm < 4; ++fm)
#pragma unroll
    for (int fn = 0; fn < 4; ++fn)
#pragma unroll
      for (int r = 0; r < 4; ++r) {
        const int row = row0 + wr * 64 + fm * 16 + lg * 4 + r;
        const int col = col0 + wc * 64 + fn * 16 + lr;
        const float v = acc[fm][fn][r] * ((col < n_scaled) ? scale : 1.f);
        if (out_bf) ((bf16_t*)Cout)[(size_t)row * N + col] = (bf16_t)v;
        else        ((float*)Cout)[(size_t)row * N + col] = v;
      }
}

// -------- rmsnorm + rotary + v-augment + gate sigmoids, bf16 out --------
// qkv_b is bf16 (B*T, QN_): cols [0,3072) = qkv, [3072,3088) = attn-gate
// scores, [3088,3104) = ve-gate scores (both unscaled by lambda).
__global__ __launch_bounds__(256) void post_kernel(
    const bf16_t* __restrict__ qkv_b, const float* __restrict__ ve,
    const float* __restrict__ cosb, const float* __restrict__ sinb,
    bf16_t* __restrict__ q_bf, bf16_t* __restrict__ k_bf,
    bf16_t* __restrict__ v_bf, float* __restrict__ attn_gate)
{
  const int wid = (blockIdx.x * blockDim.x + threadIdx.x) >> 6;
  const int lane = threadIdx.x & 63;
  const int h = wid & (H_ - 1);
  const int t = (wid >> 4) & (T_ - 1);
  const int b = wid >> 15;
  const size_t row = (size_t)(b * T_ + t) * QN_;
  const float qraw = (float)qkv_b[row + h * HD_ + lane];
  const float kraw = (float)qkv_b[row + D_ + h * HD_ + lane];
  const float vraw = (float)qkv_b[row + 2 * D_ + h * HD_ + lane];
  const float c = cosb[t * (HD_ / 2) + (lane & 31)];
  const float s = sinb[t * (HD_ / 2) + (lane & 31)];

  float ssq = qraw * qraw;
  float ssk = kraw * kraw;
#pragma unroll
  for (int off = 32; off > 0; off >>= 1) {
    ssq += __shfl_xor(ssq, off);
    ssk += __shfl_xor(ssk, off);
  }
  const float qn = qraw * rsqrtf(ssq * (1.f / 64.f) + EPS_);
  const float kn = kraw * rsqrtf(ssk * (1.f / 64.f) + EPS_);
  const float qpartner = __shfl_xor(qn, 32);
  const float kpartner = __shfl_xor(kn, 32);
  const float qo = (lane < 32) ? fmaf(qn, c, qpartner * s)
                               : fmaf(qn, c, -qpartner * s);
  const float ko = (lane < 32) ? fmaf(kn, c, kpartner * s)
                               : fmaf(kn, c, -kpartner * s);
  const int bh = b * H_ + h;
  const size_t oidx = ((size_t)bh * T_ + t) * HD_ + lane;
  q_bf[oidx] = (bf16_t)qo;
  k_bf[oidx] = (bf16_t)ko;
  // gate scores (broadcast bf16 reads)
  const float gv = VE_SCALE_ / (1.f + __expf(-(float)qkv_b[row + 3088 + h]));
  const float vv = fmaf(gv, ve[(size_t)(b * T_ + t) * D_ + h * HD_ + lane], vraw);
  v_bf[oidx] = (bf16_t)vv;
  if (lane == 0)
    attn_gate[(b * T_ + t) * H_ + h] =
        1.f / (1.f + __expf(-(float)qkv_b[row + 3072 + h]));
}

// ---------------- MFMA flash attention, doc-block-diagonal ----------------
// Grid (32 q-tiles, 32 bh); block = 4 waves, wave w owns q-rows w*16..+16.
// docs sorted => q-tile qt only attends kt in [ktlo, qt].
__global__ __launch_bounds__(256) void attn_mfma(
    const bf16_t* __restrict__ q_buf, const bf16_t* __restrict__ k_tmp,
    const bf16_t* __restrict__ v_buf, const float* __restrict__ attn_gate,
    const int* __restrict__ docs, const float* __restrict__ scale_ptr,
    bf16_t* __restrict__ y_buf)
{
  const int qt = blockIdx.x, bh = blockIdx.y;
  const int b = bh >> 4, h = bh & 15;
  const int tid = threadIdx.x;
  const int w = tid >> 6, lane = tid & 63;
  const int lr = lane & 15, lg = lane >> 4;
  const float scale = scale_ptr[0];
  __shared__ bf16_t Ks[64][72];
  __shared__ bf16_t Vt[64][72];
  __shared__ bf16_t Ps[64][72];
  __shared__ int dk[64];

  // doc-range lower bound for this q-tile
  const int dlo = docs[qt * 64];
  const unsigned long long bal =
      __ballot((lane <= qt) && (docs[lane * 64 + 63] >= dlo));
  const int ktlo = __ffsll(bal) - 1;

  // Q a-frags hoisted (A-frag: row = lane&15, k = (lane>>4)*8+j)
  const bf16_t* qp = q_buf + ((size_t)bh * T_ + qt * 64 + w * 16 + lr) * HD_;
  const bf16x8 aq0 = *(const bf16x8*)(qp + lg * 8);
  const bf16x8 aq1 = *(const bf16x8*)(qp + 32 + lg * 8);
  int qpos_r[4], docq_r[4];
#pragma unroll
  for (int r = 0; r < 4; ++r) {
    qpos_r[r] = qt * 64 + w * 16 + lg * 4 + r;
    docq_r[r] = docs[qpos_r[r]];
  }
  f32x4 acc[4];
#pragma unroll
  for (int fn = 0; fn < 4; ++fn) acc[fn] = F4ZERO;
  float m[4] = {-1e30f, -1e30f, -1e30f, -1e30f};
  float l[4] = {0.f, 0.f, 0.f, 0.f};

#pragma unroll 1
  for (int kt = ktlo; kt <= qt; ++kt) {
    __syncthreads();
#pragma unroll
    for (int i = 0; i < 2; ++i) {
      const int idx = i * 256 + tid;
      // K staging (fused key-offset: channels [16,32)|[48,64) from t-1)
      const int krow = idx >> 3;
      const int c8 = (idx & 7) << 3;
      const int gk = kt * 64 + krow;
      const int gks = (((c8 & 16) != 0) && gk > 0) ? gk - 1 : gk;
      *(bf16x8*)&Ks[krow][c8] =
          *(const bf16x8*)(k_tmp + ((size_t)bh * T_ + gks) * HD_ + c8);
      // V transpose staging
      const int kpos = idx & 63;
      const int d0 = (idx >> 6) << 3;
      const bf16x8 vv =
          *(const bf16x8*)(v_buf + ((size_t)bh * T_ + kt * 64 + kpos) * HD_ + d0);
#pragma unroll
      for (int j = 0; j < 8; ++j) Vt[d0 + j][kpos] = vv[j];
    }
    if (tid < 64) dk[tid] = docs[kt * 64 + tid];
    __syncthreads();

    // S = Q K^T  (B-frag: col = lane&15 = kpos, k = d contiguous)
    f32x4 s[4];
#pragma unroll
    for (int fn = 0; fn < 4; ++fn) {
      const bf16x8 bk0 = *(const bf16x8*)&Ks[fn * 16 + lr][lg * 8];
      const bf16x8 bk1 = *(const bf16x8*)&Ks[fn * 16 + lr][32 + lg * 8];
      f32x4 z = F4ZERO;
      z = __builtin_amdgcn_mfma_f32_16x16x32_bf16(aq0, bk0, z, 0, 0, 0);
      s[fn] = __builtin_amdgcn_mfma_f32_16x16x32_bf16(aq1, bk1, z, 0, 0, 0);
    }
    // mask + scale (lane holds rows lg*4+r, col fn*16+lr of the 64x64 S)
    const bool strict = (kt < qt);
#pragma unroll
    for (int fn = 0; fn < 4; ++fn) {
      const int kd = dk[fn * 16 + lr];
      const int kp = kt * 64 + fn * 16 + lr;
#pragma unroll
      for (int r = 0; r < 4; ++r) {
        const bool valid = (kd == docq_r[r]) && (strict || kp <= qpos_r[r]);
        s[fn][r] = valid ? s[fn][r] * scale : -3.0e38f;
      }
    }
    // online softmax (row reduce across 16-lane col group) + P write
#pragma unroll
    for (int r = 0; r < 4; ++r) {
      float cm = fmaxf(fmaxf(s[0][r], s[1][r]), fmaxf(s[2][r], s[3][r]));
      cm = fmaxf(cm, __shfl_xor(cm, 1));
      cm = fmaxf(cm, __shfl_xor(cm, 2));
      cm = fmaxf(cm, __shfl_xor(cm, 4));
      cm = fmaxf(cm, __shfl_xor(cm, 8));
      const float mn = fmaxf(m[r], cm);
      const float sc = __expf(m[r] - mn);
      m[r] = mn;
      const float p0 = __expf(s[0][r] - mn);
      const float p1 = __expf(s[1][r] - mn);
      const float p2 = __expf(s[2][r] - mn);
      const float p3 = __expf(s[3][r] - mn);
      float ps = (p0 + p1) + (p2 + p3);
      ps += __shfl_xor(ps, 1);
      ps += __shfl_xor(ps, 2);
      ps += __shfl_xor(ps, 4);
      ps += __shfl_xor(ps, 8);
      l[r] = l[r] * sc + ps;
      acc[0][r] *= sc; acc[1][r] *= sc; acc[2][r] *= sc; acc[3][r] *= sc;
      const int prow = w * 16 + lg * 4 + r;
      Ps[prow][0 + lr]  = (bf16_t)p0;
      Ps[prow][16 + lr] = (bf16_t)p1;
      Ps[prow][32 + lr] = (bf16_t)p2;
      Ps[prow][48 + lr] = (bf16_t)p3;
    }
    // PV: A = P rows (wave-private LDS slice), B = Vt rows (col = d)
    const bf16x8 ap0 = *(const bf16x8*)&Ps[w * 16 + lr][lg * 8];
    const bf16x8 ap1 = *(const bf16x8*)&Ps[w * 16 + lr][32 + lg * 8];
#pragma unroll
    for (int fn = 0; fn < 4; ++fn) {
      const bf16x8 bv0 = *(const bf16x8*)&Vt[fn * 16 + lr][lg * 8];
      const bf16x8 bv1 = *(const bf16x8*)&Vt[fn * 16 + lr][32 + lg * 8];
      acc[fn] = __builtin_amdgcn_mfma_f32_16x16x32_bf16(ap0, bv0, acc[fn], 0, 0, 0);
      acc[fn] = __builtin_amdgcn_mfma_f32_16x16x32_bf16(ap1, bv1, acc[fn], 0, 0, 0);
    }
  }
  // epilogue: gate & normalize, write bf16 y (B,T,D)
#pragma unroll
  for (int r = 0; r < 4; ++r) {
    const float inv = attn_gate[(size_t)(b * T_ + qpos_r[r]) * H_ + h] / l[r];
#pragma unroll
    for (int fn = 0; fn < 4; ++fn)
      y_buf[(size_t)(b * T_ + qpos_r[r]) * D_ + h * HD_ + fn * 16 + lr] =
          (bf16_t)(acc[fn][r] * inv);
  }
}

extern "C" void kernel_launch(void* const* d_in, const int* in_sizes, int n_in,
                              void* d_out, int out_size, void* d_ws, size_t ws_size,
                              hipStream_t stream) {
  const float* x    = (const float*)d_in[0];
  const float* ve   = (const float*)d_in[1];
  const float* lam  = (const float*)d_in[2];
  const float* cosb = (const float*)d_in[3];
  const float* sinb = (const float*)d_in[4];
  const float* qkvo = (const float*)d_in[5];
  const float* agw  = (const float*)d_in[6];
  const float* vgw  = (const float*)d_in[7];
  const float* ascl = (const float*)d_in[8];
  const int*   docs = (const int*)d_in[9];
  float* out = (float*)d_out;

  const size_t BT = (size_t)B_ * T_;  // 4096
  float* cur = (float*)d_ws;
  bf16_t* x_bf = (bf16_t*)cur;        cur += BT * D_ / 2;
  bf16_t* wq_bf = (bf16_t*)cur;       cur += (size_t)QN_ * D_ / 2;   // [3200][1024]
  bf16_t* wo_bf = (bf16_t*)cur;       cur += (size_t)D_ * D_ / 2;
  bf16_t* qkv_b = (bf16_t*)cur;       cur += BT * QN_ / 2;
  bf16_t* q_bf = (bf16_t*)cur;        cur += BT * D_ / 2;
  bf16_t* k_bf = (bf16_t*)cur;        cur += BT * D_ / 2;
  bf16_t* v_bf = (bf16_t*)cur;        cur += BT * D_ / 2;
  bf16_t* y_bf = (bf16_t*)cur;        cur += BT * D_ / 2;
  float* attn_gate = cur;             cur += BT * H_;

  // casts: x, qkv weight rows (0..3071), gate weight rows (3072..3103), Wo
  const int nx4 = (int)(BT * D_ / 4);
  cast_bf16<<<(nx4 + 255) / 256, 256, 0, stream>>>(x, x_bf, nx4);
  const int nwq4 = (int)((size_t)3 * D_ * D_ / 4);
  cast_bf16<<<(nwq4 + 255) / 256, 256, 0, stream>>>(qkvo, wq_bf, nwq4);
  const int ng4 = (int)((size_t)H_ * D_ / 4);
  cast_bf16<<<(ng4 + 255) / 256, 256, 0, stream>>>(agw, wq_bf + (size_t)3072 * D_, ng4);
  cast_bf16<<<(ng4 + 255) / 256, 256, 0, stream>>>(vgw, wq_bf + (size_t)3088 * D_, ng4);
  const int nwo4 = (int)((size_t)D_ * D_ / 4);
  cast_bf16<<<(nwo4 + 255) / 256, 256, 0, stream>>>(qkvo + (size_t)3 * D_ * D_, wo_bf, nwo4);

  // 1) QKV + gate-score projection (bf16 MFMA, bf16 out, gates unscaled)
  gemm_bf16<<<dim3(QN_ / 128, BT / 128), 256, 0, stream>>>(
      x_bf, wq_bf, qkv_b, (int)BT, QN_, D_, lam, 0, 3072, 1);

  // 2) rmsnorm + rotary + v-augment + gate sigmoids -> bf16 q/k/v (B,H,T,HD)
  post_kernel<<<(B_ * T_ * H_) / 4, 256, 0, stream>>>(
      qkv_b, ve, cosb, sinb, q_bf, k_bf, v_bf, attn_gate);

  // 3) MFMA flash attention (doc-block-diagonal skip; key-offset fused)
  attn_mfma<<<dim3(T_ / 64, B_ * H_), 256, 0, stream>>>(
      q_bf, k_bf, v_bf, attn_gate, docs, ascl, y_bf);

  // 4) output projection (bf16 MFMA, f32 out)
  gemm_bf16<<<dim3(D_ / 128, BT / 128), 256, 0, stream>>>(
      y_bf, wo_bf, out, (int)BT, D_, D_, lam, 1, D_, 0);
}